// Round 1
// 259.069 us; speedup vs baseline: 1.0325x; 1.0325x over previous
//
#include <hip/hip_runtime.h>

// FNet 2D FFT real part, Hermitian-optimized 3-pass plan (v2: latency-focused).
// x[8][4096][768] fp32 -> Re(FFT2(x)) over (seq, hidden).
//
// Pass 1 (fft_hidden): pack row pairs z = x[2r] + i*x[2r+1]; 768 = 3*4^4 FFT.
//   Stage 1 (radix-3) fused with the global load (float2 vector loads, no
//   staging round-trip). Stages 2..5 radix-4, IN-PLACE single 13 KB LDS buffer
//   (read-all / barrier / write-all) -> 8 blocks/CU occupancy cap (was 6).
//   Unpack conjugate symmetry, store transposed planes [b][k2][n1] (k2<=384).
// Pass 2 (fft_seq): 4096 = 8^4, radix-8 x 4 stages (Volkov formulation).
//   Stage 1 fused with global load (twiddle-free), stage 4 fused with global
//   store (natural order) -> 3 LDS round-trips, 5 barriers (was 8 / 12).
// Pass 3 (transpose_mirror): float4 tile transpose + Hermitian mirror.
//
// Both FFT passes use padded LDS indexing phys = i + (i>>4): every stage's
// read/write pattern becomes bank-uniform (kills the 16-way conflicts the
// radix write patterns otherwise produce on 8B accesses).

constexpr int HN = 768;
constexpr int SN = 4096;
constexpr int KH = 385;   // Hermitian-unique hidden frequencies 0..384
constexpr float PI2 = 6.283185307179586f;

static __device__ __forceinline__ float2 cadd(float2 a, float2 b) { return make_float2(a.x + b.x, a.y + b.y); }
static __device__ __forceinline__ float2 csub(float2 a, float2 b) { return make_float2(a.x - b.x, a.y - b.y); }
static __device__ __forceinline__ float2 cmul(float2 a, float2 b) { return make_float2(a.x * b.x - a.y * b.y, a.x * b.y + a.y * b.x); }
static __device__ __forceinline__ int pad(int i) { return i + (i >> 4); }

static __device__ __forceinline__ void bfly4(float2 v0, float2 v1, float2 v2, float2 v3,
                                             float2& V0, float2& V1, float2& V2, float2& V3) {
  float2 t0 = cadd(v0, v2), t1 = csub(v0, v2);
  float2 t2 = cadd(v1, v3), t3 = csub(v1, v3);
  float2 t3i = make_float2(t3.y, -t3.x);   // -i * t3
  V0 = cadd(t0, t2); V2 = csub(t0, t2);
  V1 = cadd(t1, t3i); V3 = csub(t1, t3i);
}

// Forward DFT-8 (W = e^{-2pi i/8}), in place on v[0..7].
static __device__ __forceinline__ void dft8(float2 v[8]) {
  const float C = 0.70710678118654752f;
  float2 e0, e1, e2, e3, o0, o1, o2, o3;
  {
    float2 t0 = cadd(v[0], v[4]), t1 = csub(v[0], v[4]);
    float2 t2 = cadd(v[2], v[6]), t3u = csub(v[2], v[6]);
    float2 t3 = make_float2(t3u.y, -t3u.x);
    e0 = cadd(t0, t2); e1 = cadd(t1, t3); e2 = csub(t0, t2); e3 = csub(t1, t3);
  }
  {
    float2 t0 = cadd(v[1], v[5]), t1 = csub(v[1], v[5]);
    float2 t2 = cadd(v[3], v[7]), t3u = csub(v[3], v[7]);
    float2 t3 = make_float2(t3u.y, -t3u.x);
    o0 = cadd(t0, t2); o1 = cadd(t1, t3); o2 = csub(t0, t2); o3 = csub(t1, t3);
  }
  // rotate odd outputs by w8^k: w8^1 = C(1-i), w8^2 = -i, w8^3 = C(-1-i)
  float2 r1 = make_float2(C * (o1.x + o1.y), C * (o1.y - o1.x));
  float2 r2 = make_float2(o2.y, -o2.x);
  float2 r3 = make_float2(C * (o3.y - o3.x), -C * (o3.x + o3.y));
  v[0] = cadd(e0, o0); v[4] = csub(e0, o0);
  v[1] = cadd(e1, r1); v[5] = csub(e1, r1);
  v[2] = cadd(e2, r2); v[6] = csub(e2, r2);
  v[3] = cadd(e3, r3); v[7] = csub(e3, r3);
}

// Twiddle v[q] *= W^(q*jm), W = e^{-2pi i * invDen}, invDen = 1/(8*Ns).
static __device__ __forceinline__ void twiddle8(float2 v[8], int jm, float invDen) {
  const float ang = -PI2 * (float)jm * invDen;
  float s1, c1; __sincosf(ang, &s1, &c1);
  const float2 w1 = make_float2(c1, s1);
  const float2 w2 = cmul(w1, w1);
  const float2 w3 = cmul(w2, w1);
  const float2 w4 = cmul(w2, w2);
  const float2 w5 = cmul(w4, w1);
  const float2 w6 = cmul(w3, w3);
  const float2 w7 = cmul(w4, w3);
  v[1] = cmul(v[1], w1); v[2] = cmul(v[2], w2); v[3] = cmul(v[3], w3);
  v[4] = cmul(v[4], w4); v[5] = cmul(v[5], w5); v[6] = cmul(v[6], w6);
  v[7] = cmul(v[7], w7);
}

// ---------------- Pass 1: hidden FFT (768 = 3 * 4^4), 2 packed complex rows = 4 real rows ----------------
__global__ __launch_bounds__(256, 6)
void fft_hidden(const float* __restrict__ x, float* __restrict__ wRe, float* __restrict__ wIm) {
  __shared__ float2 buf[1631];   // pad(1535)+1 -> 13.0 KB, in-place single buffer
  const int tid = threadIdx.x;
  const int blk = blockIdx.x;       // 8192 blocks
  const int b = blk & 7;            // batch pinned per XCD
  const int n0 = (blk >> 3) * 4;    // first of 4 real rows
  const float* xb = x + (size_t)b * SN * HN;

  // ---- stage 1 (radix-3, Ns=1, no twiddle) fused with global load.
  // thread: complex row = tid>>7, two adjacent butterflies j0, j0+1.
  {
    const int row = tid >> 7;
    const int j0 = (tid & 127) * 2;
    const float* r0 = xb + (size_t)(n0 + 2 * row) * HN;
    const float* r1 = r0 + HN;
    const float2 a0 = *(const float2*)(r0 + j0);
    const float2 a1 = *(const float2*)(r0 + j0 + 256);
    const float2 a2 = *(const float2*)(r0 + j0 + 512);
    const float2 b0 = *(const float2*)(r1 + j0);
    const float2 b1 = *(const float2*)(r1 + j0 + 256);
    const float2 b2 = *(const float2*)(r1 + j0 + 512);
    const float cc = -0.5f, ss = -0.8660254037844386f;
    const int base = row * HN + 3 * j0;
#pragma unroll
    for (int e = 0; e < 2; ++e) {
      const float2 v0 = e ? make_float2(a0.y, b0.y) : make_float2(a0.x, b0.x);
      const float2 v1 = e ? make_float2(a1.y, b1.y) : make_float2(a1.x, b1.x);
      const float2 v2 = e ? make_float2(a2.y, b2.y) : make_float2(a2.x, b2.x);
      const float tr = v1.x + v2.x, ti = v1.y + v2.y;
      const float ur = v1.x - v2.x, ui = v1.y - v2.y;
      const int o = base + 3 * e;
      buf[pad(o)]     = make_float2(v0.x + tr, v0.y + ti);
      buf[pad(o + 1)] = make_float2(v0.x + cc * tr - ss * ui, v0.y + cc * ti + ss * ur);
      buf[pad(o + 2)] = make_float2(v0.x + cc * tr + ss * ui, v0.y + cc * ti - ss * ur);
    }
  }
  __syncthreads();

  // ---- stages 2..5: radix-4, Ns = 3, 12, 48, 192, in-place (read / barrier / write / barrier).
  int Ns = 3;
  const float invD[4] = {1.f / 12.f, 1.f / 48.f, 1.f / 192.f, 1.f / 768.f};
#pragma unroll
  for (int st = 0; st < 4; ++st) {
    float2 V[2][4];
    int idxD[2];
#pragma unroll
    for (int it = 0; it < 2; ++it) {
      const int w = tid + it * 256;
      if (w < 384) {
        const int row = (w >= 192) ? 1 : 0;
        const int j = w - row * 192;
        const int rb = row * HN;
        float2 v0 = buf[pad(rb + j)];
        float2 v1 = buf[pad(rb + j + 192)];
        float2 v2 = buf[pad(rb + j + 384)];
        float2 v3 = buf[pad(rb + j + 576)];
        const int jm = j % Ns;
        const float ang = -PI2 * (float)jm * invD[st];
        float s1, c1; __sincosf(ang, &s1, &c1);
        const float2 w1 = make_float2(c1, s1);
        const float2 w2 = cmul(w1, w1);
        const float2 w3 = cmul(w2, w1);
        v1 = cmul(v1, w1); v2 = cmul(v2, w2); v3 = cmul(v3, w3);
        bfly4(v0, v1, v2, v3, V[it][0], V[it][1], V[it][2], V[it][3]);
        idxD[it] = rb + (j / Ns) * (Ns * 4) + jm;
      }
    }
    __syncthreads();
#pragma unroll
    for (int it = 0; it < 2; ++it) {
      const int w = tid + it * 256;
      if (w < 384) {
        buf[pad(idxD[it])]          = V[it][0];
        buf[pad(idxD[it] + Ns)]     = V[it][1];
        buf[pad(idxD[it] + 2 * Ns)] = V[it][2];
        buf[pad(idxD[it] + 3 * Ns)] = V[it][3];
      }
    }
    __syncthreads();
    Ns *= 4;
  }

  // ---- unpack conjugate symmetry + transposed Hermitian store (k2 in [0,384]).
  for (int k = tid; k < KH; k += 256) {
    const int km = (k == 0) ? 0 : (HN - k);
    const float2 Z0 = buf[pad(k)],      Z0m = buf[pad(km)];
    const float2 Z1 = buf[pad(HN + k)], Z1m = buf[pad(HN + km)];
    float4 re, im;
    re.x = 0.5f * (Z0.x + Z0m.x);  im.x = 0.5f * (Z0.y - Z0m.y);
    re.y = 0.5f * (Z0.y + Z0m.y);  im.y = 0.5f * (Z0m.x - Z0.x);
    re.z = 0.5f * (Z1.x + Z1m.x);  im.z = 0.5f * (Z1.y - Z1m.y);
    re.w = 0.5f * (Z1.y + Z1m.y);  im.w = 0.5f * (Z1m.x - Z1.x);
    const size_t o = (((size_t)(b * KH + k)) * SN + n0) >> 2;  // float4 index, n0 % 4 == 0
    ((float4*)wRe)[o] = re;
    ((float4*)wIm)[o] = im;
  }
}

// ---------------- Pass 2: seq FFT (4096 = 8^4), radix-8 x 4, fused ends ----------------
__global__ __launch_bounds__(512, 4)
void fft_seq(float* __restrict__ wRe, const float* __restrict__ wIm) {
  __shared__ float2 buf[4351];   // pad(4095)+1 -> 34.8 KB
  const int tid = threadIdx.x;
  const int blk = blockIdx.x;              // 3080 blocks = 8 * 385
  const int b = blk & 7;
  const int k2 = blk >> 3;
  const size_t base = ((size_t)b * KH + k2) * SN;
  const float* re = wRe + base;
  const float* im = wIm + base;

  float2 v[8];

  // ---- stage 1: Ns=1 (twiddle-free), fused with global load
#pragma unroll
  for (int q = 0; q < 8; ++q)
    v[q] = make_float2(re[tid + q * 512], im[tid + q * 512]);
  dft8(v);
#pragma unroll
  for (int q = 0; q < 8; ++q)
    buf[pad(8 * tid + q)] = v[q];
  __syncthreads();

  // ---- stages 2,3: Ns = 8, 64, in-place
  int Ns = 8;
  const float invD2[2] = {1.f / 64.f, 1.f / 512.f};
#pragma unroll
  for (int st = 0; st < 2; ++st) {
#pragma unroll
    for (int q = 0; q < 8; ++q)
      v[q] = buf[pad(tid + q * 512)];
    const int jm = tid & (Ns - 1);
    twiddle8(v, jm, invD2[st]);
    dft8(v);
    const int idxD = ((tid & ~(Ns - 1)) << 3) + jm;
    __syncthreads();   // all reads done before any in-place writes
#pragma unroll
    for (int q = 0; q < 8; ++q)
      buf[pad(idxD + q * Ns)] = v[q];
    __syncthreads();
    Ns <<= 3;
  }

  // ---- stage 4: Ns = 512, natural-order output, write Re directly to global
#pragma unroll
  for (int q = 0; q < 8; ++q)
    v[q] = buf[pad(tid + q * 512)];
  twiddle8(v, tid, 1.f / 4096.f);
  dft8(v);
  float* outp = wRe + base;
#pragma unroll
  for (int q = 0; q < 8; ++q)
    outp[tid + q * 512] = v[q].x;
}

// ---------------- Pass 3: transpose + Hermitian mirror (vectorized) ----------------
// ws[b][k2'][k1] (k2' in [0,384]) -> out[b][k1][k2'] and out[b][(4096-k1)%4096][768-k2']
__global__ __launch_bounds__(256)
void transpose_mirror(const float* __restrict__ ws, float* __restrict__ out) {
  __shared__ float tile[32][33];
  const int b = blockIdx.z;
  const int k1_0 = blockIdx.x * 32;
  const int k2_0 = blockIdx.y * 32;
  const float* ib = ws + (size_t)b * KH * SN;
  float* ob = out + (size_t)b * SN * HN;
  const int t = threadIdx.x;

  // read: 32 k2-rows x 8 float4 (one per thread)
  {
    const int k2l = t >> 3;
    const int f4 = (t & 7) * 4;
    const int k2 = k2_0 + k2l;
    if (k2 < KH) {
      const float4 vv = *(const float4*)(ib + (size_t)k2 * SN + k1_0 + f4);
      tile[k2l][f4]     = vv.x;
      tile[k2l][f4 + 1] = vv.y;
      tile[k2l][f4 + 2] = vv.z;
      tile[k2l][f4 + 3] = vv.w;
    }
  }
  __syncthreads();

  // write: 32 k1-rows x 8 col-groups of 4 (one per thread)
  {
    const int k1l = t >> 3;
    const int cg = (t & 7) * 4;
    const int k1 = k1_0 + k1l;
    const int c = k2_0 + cg;             // source k2 of w[0]
    const float w0 = tile[cg][k1l];
    const float w1 = tile[cg + 1][k1l];
    const float w2 = tile[cg + 2][k1l];
    const float w3 = tile[cg + 3][k1l];
    float* orow = ob + (size_t)k1 * HN;
    float* mrow = ob + (size_t)((SN - k1) & (SN - 1)) * HN;

    if (c + 3 <= 384) {
      *(float4*)(orow + c) = make_float4(w0, w1, w2, w3);   // 16B aligned (c % 4 == 0)
    } else {
#pragma unroll
      for (int j = 0; j < 4; ++j) {
        const int k2 = c + j;
        const float wv = (j == 0) ? w0 : (j == 1) ? w1 : (j == 2) ? w2 : w3;
        if (k2 <= 384) orow[k2] = wv;
      }
    }
    // mirror: k2 in [1,383] -> column 768-k2 (range is 4-misaligned -> scalar)
#pragma unroll
    for (int j = 0; j < 4; ++j) {
      const int k2 = c + j;
      const float wv = (j == 0) ? w0 : (j == 1) ? w1 : (j == 2) ? w2 : w3;
      if (k2 >= 1 && k2 <= HN - KH)
        mrow[HN - k2] = wv;
    }
  }
}

extern "C" void kernel_launch(void* const* d_in, const int* in_sizes, int n_in,
                              void* d_out, int out_size, void* d_ws, size_t ws_size,
                              hipStream_t stream) {
  const float* x = (const float*)d_in[0];
  float* out = (float*)d_out;
  float* wRe = (float*)d_ws;   // 8*385*4096 floats = 50.5 MB
  float* wIm = out;            // reuse output buffer as Im scratch (dead after pass 2)

  fft_hidden<<<8192, 256, 0, stream>>>(x, wRe, wIm);
  fft_seq<<<3080, 512, 0, stream>>>(wRe, wIm);
  transpose_mirror<<<dim3(SN / 32, (KH + 31) / 32, 8), dim3(256, 1, 1), 0, stream>>>(wRe, out);
}

// Round 2
// 252.469 us; speedup vs baseline: 1.0595x; 1.0261x over previous
//
#include <hip/hip_runtime.h>

// FNet 2D FFT real part, Hermitian-optimized 3-pass plan (v3: store granularity).
// x[8][4096][768] fp32 -> Re(FFT2(x)) over (seq, hidden).
//
// Pass 1 (fft_hidden): 16 real rows per block (8 complex packed rows), 512 thr.
//   Radix-3 stage fused with global load; radix-4 x4 in-place in one 52 KB LDS
//   buffer. Unpack writes 64 B contiguous per k2 row per block (4 back-to-back
//   float4 from the same lane) -> L2 can assemble full lines (v2's 4-row blocks
//   left 16 B fragments to be merged across unrelated blocks: WRITE_SIZE 160 MB
//   vs 101 ideal).
// Pass 2 (fft_seq): 4096 = 8^4 radix-8, ends fused with global load/store.
// Pass 3 (transpose_mirror): 64(k1) x 32(k2) tiles, 512 thr, 256 B reads.

constexpr int HN = 768;
constexpr int SN = 4096;
constexpr int KH = 385;   // Hermitian-unique hidden frequencies 0..384
constexpr float PI2 = 6.283185307179586f;

static __device__ __forceinline__ float2 cadd(float2 a, float2 b) { return make_float2(a.x + b.x, a.y + b.y); }
static __device__ __forceinline__ float2 csub(float2 a, float2 b) { return make_float2(a.x - b.x, a.y - b.y); }
static __device__ __forceinline__ float2 cmul(float2 a, float2 b) { return make_float2(a.x * b.x - a.y * b.y, a.x * b.y + a.y * b.x); }
static __device__ __forceinline__ int pad(int i) { return i + (i >> 4); }

static __device__ __forceinline__ void bfly4(float2 v0, float2 v1, float2 v2, float2 v3,
                                             float2& V0, float2& V1, float2& V2, float2& V3) {
  float2 t0 = cadd(v0, v2), t1 = csub(v0, v2);
  float2 t2 = cadd(v1, v3), t3 = csub(v1, v3);
  float2 t3i = make_float2(t3.y, -t3.x);   // -i * t3
  V0 = cadd(t0, t2); V2 = csub(t0, t2);
  V1 = cadd(t1, t3i); V3 = csub(t1, t3i);
}

// Forward DFT-8 (W = e^{-2pi i/8}), in place on v[0..7].
static __device__ __forceinline__ void dft8(float2 v[8]) {
  const float C = 0.70710678118654752f;
  float2 e0, e1, e2, e3, o0, o1, o2, o3;
  {
    float2 t0 = cadd(v[0], v[4]), t1 = csub(v[0], v[4]);
    float2 t2 = cadd(v[2], v[6]), t3u = csub(v[2], v[6]);
    float2 t3 = make_float2(t3u.y, -t3u.x);
    e0 = cadd(t0, t2); e1 = cadd(t1, t3); e2 = csub(t0, t2); e3 = csub(t1, t3);
  }
  {
    float2 t0 = cadd(v[1], v[5]), t1 = csub(v[1], v[5]);
    float2 t2 = cadd(v[3], v[7]), t3u = csub(v[3], v[7]);
    float2 t3 = make_float2(t3u.y, -t3u.x);
    o0 = cadd(t0, t2); o1 = cadd(t1, t3); o2 = csub(t0, t2); o3 = csub(t1, t3);
  }
  float2 r1 = make_float2(C * (o1.x + o1.y), C * (o1.y - o1.x));
  float2 r2 = make_float2(o2.y, -o2.x);
  float2 r3 = make_float2(C * (o3.y - o3.x), -C * (o3.x + o3.y));
  v[0] = cadd(e0, o0); v[4] = csub(e0, o0);
  v[1] = cadd(e1, r1); v[5] = csub(e1, r1);
  v[2] = cadd(e2, r2); v[6] = csub(e2, r2);
  v[3] = cadd(e3, r3); v[7] = csub(e3, r3);
}

// Twiddle v[q] *= W^(q*jm), W = e^{-2pi i * invDen}, invDen = 1/(8*Ns).
static __device__ __forceinline__ void twiddle8(float2 v[8], int jm, float invDen) {
  const float ang = -PI2 * (float)jm * invDen;
  float s1, c1; __sincosf(ang, &s1, &c1);
  const float2 w1 = make_float2(c1, s1);
  const float2 w2 = cmul(w1, w1);
  const float2 w3 = cmul(w2, w1);
  const float2 w4 = cmul(w2, w2);
  const float2 w5 = cmul(w4, w1);
  const float2 w6 = cmul(w3, w3);
  const float2 w7 = cmul(w4, w3);
  v[1] = cmul(v[1], w1); v[2] = cmul(v[2], w2); v[3] = cmul(v[3], w3);
  v[4] = cmul(v[4], w4); v[5] = cmul(v[5], w5); v[6] = cmul(v[6], w6);
  v[7] = cmul(v[7], w7);
}

// ---------------- Pass 1: hidden FFT (768 = 3 * 4^4), 8 packed complex rows = 16 real rows ----------------
__global__ __launch_bounds__(512, 6)
void fft_hidden(const float* __restrict__ x, float* __restrict__ wRe, float* __restrict__ wIm) {
  __shared__ float2 buf[6528];   // pad(6143)=6526 -> 52.2 KB, 3 blocks/CU
  const int tid = threadIdx.x;
  const int blk = blockIdx.x;       // 2048 blocks
  const int b = blk & 7;            // batch pinned per XCD
  const int n0 = (blk >> 3) * 16;   // first of 16 real rows
  const float* xb = x + (size_t)b * SN * HN;

  // ---- stage 1 (radix-3, Ns=1, no twiddle) fused with global load.
  // 8 complex rows x 128 butterfly-pairs = 1024 items; 2 per thread.
#pragma unroll
  for (int it = 0; it < 2; ++it) {
    const int w = tid + it * 512;
    const int row = w >> 7;           // complex row 0..7
    const int j0 = (w & 127) * 2;
    const float* r0 = xb + (size_t)(n0 + 2 * row) * HN;
    const float* r1 = r0 + HN;
    const float2 a0 = *(const float2*)(r0 + j0);
    const float2 a1 = *(const float2*)(r0 + j0 + 256);
    const float2 a2 = *(const float2*)(r0 + j0 + 512);
    const float2 b0 = *(const float2*)(r1 + j0);
    const float2 b1 = *(const float2*)(r1 + j0 + 256);
    const float2 b2 = *(const float2*)(r1 + j0 + 512);
    const float cc = -0.5f, ss = -0.8660254037844386f;
    const int base = row * HN + 3 * j0;
#pragma unroll
    for (int e = 0; e < 2; ++e) {
      const float2 v0 = e ? make_float2(a0.y, b0.y) : make_float2(a0.x, b0.x);
      const float2 v1 = e ? make_float2(a1.y, b1.y) : make_float2(a1.x, b1.x);
      const float2 v2 = e ? make_float2(a2.y, b2.y) : make_float2(a2.x, b2.x);
      const float tr = v1.x + v2.x, ti = v1.y + v2.y;
      const float ur = v1.x - v2.x, ui = v1.y - v2.y;
      const int o = base + 3 * e;
      buf[pad(o)]     = make_float2(v0.x + tr, v0.y + ti);
      buf[pad(o + 1)] = make_float2(v0.x + cc * tr - ss * ui, v0.y + cc * ti + ss * ur);
      buf[pad(o + 2)] = make_float2(v0.x + cc * tr + ss * ui, v0.y + cc * ti - ss * ur);
    }
  }
  __syncthreads();

  // ---- stages 2..5: radix-4, Ns = 3, 12, 48, 192, in-place.
  // 8 rows x 192 butterflies = 1536 items = 3 per thread exactly (no guards).
  int Ns = 3;
  const float invD[4] = {1.f / 12.f, 1.f / 48.f, 1.f / 192.f, 1.f / 768.f};
#pragma unroll
  for (int st = 0; st < 4; ++st) {
    float2 V[3][4];
    int idxD[3];
#pragma unroll
    for (int it = 0; it < 3; ++it) {
      const int w = tid + it * 512;
      const int row = w / 192;
      const int j = w - row * 192;
      const int rb = row * HN;
      float2 v0 = buf[pad(rb + j)];
      float2 v1 = buf[pad(rb + j + 192)];
      float2 v2 = buf[pad(rb + j + 384)];
      float2 v3 = buf[pad(rb + j + 576)];
      const int jm = j % Ns;
      const float ang = -PI2 * (float)jm * invD[st];
      float s1, c1; __sincosf(ang, &s1, &c1);
      const float2 w1 = make_float2(c1, s1);
      const float2 w2 = cmul(w1, w1);
      const float2 w3 = cmul(w2, w1);
      v1 = cmul(v1, w1); v2 = cmul(v2, w2); v3 = cmul(v3, w3);
      bfly4(v0, v1, v2, v3, V[it][0], V[it][1], V[it][2], V[it][3]);
      idxD[it] = rb + (j / Ns) * (Ns * 4) + jm;
    }
    __syncthreads();
#pragma unroll
    for (int it = 0; it < 3; ++it) {
      buf[pad(idxD[it])]          = V[it][0];
      buf[pad(idxD[it] + Ns)]     = V[it][1];
      buf[pad(idxD[it] + 2 * Ns)] = V[it][2];
      buf[pad(idxD[it] + 3 * Ns)] = V[it][3];
    }
    __syncthreads();
    Ns *= 4;
  }

  // ---- unpack conjugate symmetry + transposed Hermitian store (k2 in [0,384]).
  // Per k2: 16 Re + 16 Im contiguous floats (64 B runs per buffer) from one lane.
  for (int k = tid; k < KH; k += 512) {
    const int km = (k == 0) ? 0 : (HN - k);
    float reV[16], imV[16];
#pragma unroll
    for (int r = 0; r < 8; ++r) {
      const float2 Z  = buf[pad(r * HN + k)];
      const float2 Zm = buf[pad(r * HN + km)];
      reV[2 * r]     = 0.5f * (Z.x + Zm.x);
      imV[2 * r]     = 0.5f * (Z.y - Zm.y);
      reV[2 * r + 1] = 0.5f * (Z.y + Zm.y);
      imV[2 * r + 1] = 0.5f * (Zm.x - Z.x);
    }
    const size_t o = ((size_t)(b * KH + k)) * SN + n0;   // 64 B aligned
#pragma unroll
    for (int i = 0; i < 4; ++i) {
      *(float4*)(wRe + o + 4 * i) = make_float4(reV[4 * i], reV[4 * i + 1], reV[4 * i + 2], reV[4 * i + 3]);
      *(float4*)(wIm + o + 4 * i) = make_float4(imV[4 * i], imV[4 * i + 1], imV[4 * i + 2], imV[4 * i + 3]);
    }
  }
}

// ---------------- Pass 2: seq FFT (4096 = 8^4), radix-8 x 4, fused ends ----------------
__global__ __launch_bounds__(512, 4)
void fft_seq(float* __restrict__ wRe, const float* __restrict__ wIm) {
  __shared__ float2 buf[4351];   // pad(4095)+1 -> 34.8 KB
  const int tid = threadIdx.x;
  const int blk = blockIdx.x;              // 3080 blocks = 8 * 385
  const int b = blk & 7;
  const int k2 = blk >> 3;
  const size_t base = ((size_t)b * KH + k2) * SN;
  const float* re = wRe + base;
  const float* im = wIm + base;

  float2 v[8];

  // ---- stage 1: Ns=1 (twiddle-free), fused with global load
#pragma unroll
  for (int q = 0; q < 8; ++q)
    v[q] = make_float2(re[tid + q * 512], im[tid + q * 512]);
  dft8(v);
#pragma unroll
  for (int q = 0; q < 8; ++q)
    buf[pad(8 * tid + q)] = v[q];
  __syncthreads();

  // ---- stages 2,3: Ns = 8, 64, in-place
  int Ns = 8;
  const float invD2[2] = {1.f / 64.f, 1.f / 512.f};
#pragma unroll
  for (int st = 0; st < 2; ++st) {
#pragma unroll
    for (int q = 0; q < 8; ++q)
      v[q] = buf[pad(tid + q * 512)];
    const int jm = tid & (Ns - 1);
    twiddle8(v, jm, invD2[st]);
    dft8(v);
    const int idxD = ((tid & ~(Ns - 1)) << 3) + jm;
    __syncthreads();   // all reads done before any in-place writes
#pragma unroll
    for (int q = 0; q < 8; ++q)
      buf[pad(idxD + q * Ns)] = v[q];
    __syncthreads();
    Ns <<= 3;
  }

  // ---- stage 4: Ns = 512, natural-order output, write Re directly to global
#pragma unroll
  for (int q = 0; q < 8; ++q)
    v[q] = buf[pad(tid + q * 512)];
  twiddle8(v, tid, 1.f / 4096.f);
  dft8(v);
  float* outp = wRe + base;
#pragma unroll
  for (int q = 0; q < 8; ++q)
    outp[tid + q * 512] = v[q].x;
}

// ---------------- Pass 3: transpose + Hermitian mirror (64 x 32 tiles, 512 thr) ----------------
// ws[b][k2'][k1] (k2' in [0,384]) -> out[b][k1][k2'] and out[b][(4096-k1)%4096][768-k2']
__global__ __launch_bounds__(512)
void transpose_mirror(const float* __restrict__ ws, float* __restrict__ out) {
  __shared__ float tile[32][65];   // [k2-local][k1-local], +1 col pad
  const int b = blockIdx.z;
  const int k1_0 = blockIdx.x * 64;
  const int k2_0 = blockIdx.y * 32;
  const float* ib = ws + (size_t)b * KH * SN;
  float* ob = out + (size_t)b * SN * HN;
  const int t = threadIdx.x;

  // read: 32 k2-rows x 16 lanes x float4 = 256 B contiguous per row
  {
    const int k2l = t >> 4;
    const int fl = (t & 15) * 4;
    const int k2 = k2_0 + k2l;
    if (k2 < KH) {
      const float4 vv = *(const float4*)(ib + (size_t)k2 * SN + k1_0 + fl);
      tile[k2l][fl]     = vv.x;
      tile[k2l][fl + 1] = vv.y;
      tile[k2l][fl + 2] = vv.z;
      tile[k2l][fl + 3] = vv.w;
    }
  }
  __syncthreads();

  // write: 64 k1-rows x 8 col-groups of 4 (one per thread)
  {
    const int k1l = t >> 3;           // 0..63
    const int cg = (t & 7) * 4;       // 0..28
    const int k1 = k1_0 + k1l;
    const int c = k2_0 + cg;          // source k2 of w0
    const float w0 = tile[cg][k1l];
    const float w1 = tile[cg + 1][k1l];
    const float w2 = tile[cg + 2][k1l];
    const float w3 = tile[cg + 3][k1l];
    float* orow = ob + (size_t)k1 * HN;
    float* mrow = ob + (size_t)((SN - k1) & (SN - 1)) * HN;

    if (c + 3 <= 384) {
      *(float4*)(orow + c) = make_float4(w0, w1, w2, w3);   // 16 B aligned
    } else {
#pragma unroll
      for (int j = 0; j < 4; ++j) {
        const int k2 = c + j;
        const float wv = (j == 0) ? w0 : (j == 1) ? w1 : (j == 2) ? w2 : w3;
        if (k2 <= 384) orow[k2] = wv;
      }
    }
    // mirror: k2 in [1,383] -> column 768-k2 (4-misaligned target -> scalar)
#pragma unroll
    for (int j = 0; j < 4; ++j) {
      const int k2 = c + j;
      const float wv = (j == 0) ? w0 : (j == 1) ? w1 : (j == 2) ? w2 : w3;
      if (k2 >= 1 && k2 <= HN - KH)
        mrow[HN - k2] = wv;
    }
  }
}

extern "C" void kernel_launch(void* const* d_in, const int* in_sizes, int n_in,
                              void* d_out, int out_size, void* d_ws, size_t ws_size,
                              hipStream_t stream) {
  const float* x = (const float*)d_in[0];
  float* out = (float*)d_out;
  float* wRe = (float*)d_ws;   // 8*385*4096 floats = 50.5 MB
  float* wIm = out;            // reuse output buffer as Im scratch (dead after pass 2)

  fft_hidden<<<2048, 512, 0, stream>>>(x, wRe, wIm);
  fft_seq<<<3080, 512, 0, stream>>>(wRe, wIm);
  transpose_mirror<<<dim3(SN / 64, (KH + 31) / 32, 8), dim3(512, 1, 1), 0, stream>>>(wRe, out);
}